// Round 3
// baseline (1419.111 us; speedup 1.0000x reference)
//
#include <hip/hip_runtime.h>

#define BN 16384
#define TT 128
#define MM 4
#define SS 12
#define BLOCK 256
#define NSER (BLOCK / 4)    // 64 series per block
#define TSTRIDE 146         // doubles per series transpose region (144 + 2 pad)

__global__ __launch_bounds__(BLOCK, 1) void kf_kernel(
    const float* __restrict__ inp,   // [B][T][M]
    const float* __restrict__ Fm,    // [S][S]
    const float* __restrict__ Hm,    // [M][S]
    const float* __restrict__ Qm,    // [S][S]
    const float* __restrict__ Rm,    // [M][M]
    const float* __restrict__ m0p,   // [B][S]
    const float* __restrict__ P0p,   // [B][S][S]
    float* __restrict__ outp)        // [T][B][M]
{
    __shared__ double Fd[SS * SS];
    __shared__ double Hd[MM * SS];
    __shared__ double Qd[SS * SS];
    __shared__ double Rd[MM * MM];
    __shared__ double tb[NSER * TSTRIDE];

    const int tid  = threadIdx.x;
    const int gid  = blockIdx.x * BLOCK + tid;
    const int b    = gid >> 2;        // series
    const int c    = gid & 3;         // quad sub-lane: owns P columns {3c,3c+1,3c+2}
    const int sb   = tid >> 2;        // series-in-block
    const int col0 = 3 * c;

    if (tid < SS * SS) { Fd[tid] = (double)Fm[tid]; Qd[tid] = (double)Qm[tid]; }
    if (tid < MM * SS) Hd[tid] = (double)Hm[tid];
    if (tid < MM * MM) Rd[tid] = (double)Rm[tid];

    // filtered state (starts at m0, P0; loop begins with a predict => matches ref)
    double mf[SS];
#pragma unroll
    for (int s = 0; s < SS; ++s) mf[s] = (double)m0p[b * SS + s];

    double Pf[SS][3];
#pragma unroll
    for (int s = 0; s < SS; ++s)
#pragma unroll
        for (int jj = 0; jj < 3; ++jj)
            Pf[s][jj] = (double)P0p[b * SS * SS + s * SS + col0 + jj];

    const float* op = inp + b * (TT * MM) + c;  // own measurement stream
    float obn = op[0];
    double* tser = &tb[sb * TSTRIDE];

    __syncthreads();  // constants in LDS ready

#pragma unroll 1
    for (int t = 0; t < TT; ++t) {
        // ---------- predict: mv = F mf ; U = F Pf (col-local) ----------
        double mv[SS], Uc[SS][3];
#pragma unroll
        for (int i = 0; i < SS; ++i) {
            double fr[SS];
#pragma unroll
            for (int s = 0; s < SS; ++s) fr[s] = Fd[i * SS + s];
            double a = 0.0, u0 = 0.0, u1 = 0.0, u2 = 0.0;
#pragma unroll
            for (int s = 0; s < SS; ++s) {
                a  += fr[s] * mf[s];
                u0 += fr[s] * Pf[s][0];
                u1 += fr[s] * Pf[s][1];
                u2 += fr[s] * Pf[s][2];
            }
            mv[i] = a; Uc[i][0] = u0; Uc[i][1] = u1; Uc[i][2] = u2;
        }

        // transpose U via per-series LDS region (cross-lane within the quad)
        __syncthreads();  // prior iteration's reads done before overwrite
#pragma unroll
        for (int i = 0; i < SS; ++i) {
            tser[i * SS + col0 + 0] = Uc[i][0];
            tser[i * SS + col0 + 1] = Uc[i][1];
            tser[i * SS + col0 + 2] = Uc[i][2];
        }
        __syncthreads();
        double Ur[3][SS];  // rows {3c..3c+2} of U
#pragma unroll
        for (int jj = 0; jj < 3; ++jj)
#pragma unroll
            for (int k = 0; k < SS; ++k) Ur[jj][k] = tser[(col0 + jj) * SS + k];

        // P_prior[s][col0+jj] = (sym) Q[s][col0+jj] + sum_k U[col0+jj][k] F[s][k]
        double Pc[SS][3];
#pragma unroll
        for (int s = 0; s < SS; ++s) {
            double fr[SS];
#pragma unroll
            for (int k = 0; k < SS; ++k) fr[k] = Fd[s * SS + k];
            double p0 = Qd[s * SS + col0 + 0];
            double p1 = Qd[s * SS + col0 + 1];
            double p2 = Qd[s * SS + col0 + 2];
#pragma unroll
            for (int k = 0; k < SS; ++k) {
                p0 += Ur[0][k] * fr[k];
                p1 += Ur[1][k] * fr[k];
                p2 += Ur[2][k] * fr[k];
            }
            Pc[s][0] = p0; Pc[s][1] = p1; Pc[s][2] = p2;
        }

        // ---------- y = H mv (all 4, replicated) and HP = H * P_prior (local cols) --
        double y[MM], HPl[MM][3];
#pragma unroll
        for (int n = 0; n < MM; ++n) {
            double hr[SS];
#pragma unroll
            for (int s = 0; s < SS; ++s) hr[s] = Hd[n * SS + s];
            double a = 0.0, h0 = 0.0, h1 = 0.0, h2 = 0.0;
#pragma unroll
            for (int s = 0; s < SS; ++s) {
                a  += hr[s] * mv[s];
                h0 += hr[s] * Pc[s][0];
                h1 += hr[s] * Pc[s][1];
                h2 += hr[s] * Pc[s][2];
            }
            y[n] = a; HPl[n][0] = h0; HPl[n][1] = h1; HPl[n][2] = h2;
        }

        outp[t * (BN * MM) + b * MM + c] = (float)y[c];

        float obc = obn;
        if (t + 1 < TT) obn = op[(t + 1) * MM];  // prefetch next obs

        double r[MM];
#pragma unroll
        for (int n = 0; n < MM; ++n)
            r[n] = (double)__shfl(obc, n, 4) - y[n];

        // ---------- innovation cov: local partial + quad butterfly reduce ----------
        double Su[10];
        {
            int u = 0;
#pragma unroll
            for (int n = 0; n < MM; ++n)
#pragma unroll
                for (int t2 = n; t2 < MM; ++t2) {
                    double acc = HPl[n][0] * Hd[t2 * SS + col0 + 0]
                               + HPl[n][1] * Hd[t2 * SS + col0 + 1]
                               + HPl[n][2] * Hd[t2 * SS + col0 + 2];
                    acc += __shfl_xor(acc, 1, 4);
                    acc += __shfl_xor(acc, 2, 4);
                    Su[u++] = acc + Rd[n * MM + t2];
                }
        }
        double s00 = Su[0], s01 = Su[1], s02 = Su[2], s03 = Su[3];
        double s11 = Su[4], s12 = Su[5], s13 = Su[6];
        double s22 = Su[7], s23 = Su[8], s33 = Su[9];

        // ---------- symmetric 4x4 inverse via 2x2 Schur (fp64) ----------
        double ra   = 1.0 / (s00 * s11 - s01 * s01);
        double ai00 = s11 * ra, ai01 = -s01 * ra, ai11 = s00 * ra;
        double w00 = ai00 * s02 + ai01 * s12;
        double w01 = ai00 * s03 + ai01 * s13;
        double w10 = ai01 * s02 + ai11 * s12;
        double w11 = ai01 * s03 + ai11 * s13;
        double e00 = s22 - (s02 * w00 + s12 * w10);
        double e01 = s23 - (s02 * w01 + s12 * w11);
        double e11 = s33 - (s03 * w01 + s13 * w11);
        double rmm = 1.0 / (e00 * e11 - e01 * e01);
        double q22 = e11 * rmm, q23 = -e01 * rmm, q33 = e00 * rmm;
        double x00 = w00 * q22 + w01 * q23;
        double x01 = w00 * q23 + w01 * q33;
        double x10 = w10 * q22 + w11 * q23;
        double x11 = w10 * q23 + w11 * q33;
        double q00 = ai00 + x00 * w00 + x01 * w01;
        double q01 = ai01 + x00 * w10 + x01 * w11;
        double q11 = ai11 + x10 * w10 + x11 * w11;
        double Qi[MM][MM] = {
            { q00,  q01,  -x00, -x01 },
            { q01,  q11,  -x10, -x11 },
            { -x00, -x10,  q22,  q23 },
            { -x01, -x11,  q23,  q33 }
        };

        // ---------- z = Sinv r ; mean update (no K materialized) ----------
        double z[MM];
#pragma unroll
        for (int n = 0; n < MM; ++n)
            z[n] = Qi[n][0] * r[0] + Qi[n][1] * r[1] + Qi[n][2] * r[2] + Qi[n][3] * r[3];

        double upd[3];
#pragma unroll
        for (int jj = 0; jj < 3; ++jj)
            upd[jj] = HPl[0][jj] * z[0] + HPl[1][jj] * z[1]
                    + HPl[2][jj] * z[2] + HPl[3][jj] * z[3];

        // all-gather updated mean: source lane k/3 supplies mv[k]+upd[k%3]
#pragma unroll
        for (int k = 0; k < SS; ++k)
            mf[k] = __shfl(mv[k] + upd[k % 3], k / 3, 4);

        // ---------- covariance update: P_f = P - (HP)^T Sinv (HP) ----------
        double G[MM][3];  // G = Sinv * HP (local cols)
#pragma unroll
        for (int n = 0; n < MM; ++n)
#pragma unroll
            for (int jj = 0; jj < 3; ++jj)
                G[n][jj] = Qi[n][0] * HPl[0][jj] + Qi[n][1] * HPl[1][jj]
                         + Qi[n][2] * HPl[2][jj] + Qi[n][3] * HPl[3][jj];

#pragma unroll
        for (int s = 0; s < SS; ++s) {
            // gather HP[n][s] from the lane owning column s
            double h0 = __shfl(HPl[0][s % 3], s / 3, 4);
            double h1 = __shfl(HPl[1][s % 3], s / 3, 4);
            double h2 = __shfl(HPl[2][s % 3], s / 3, 4);
            double h3 = __shfl(HPl[3][s % 3], s / 3, 4);
#pragma unroll
            for (int jj = 0; jj < 3; ++jj)
                Pf[s][jj] = Pc[s][jj] - (h0 * G[0][jj] + h1 * G[1][jj]
                                       + h2 * G[2][jj] + h3 * G[3][jj]);
        }
    }
}

extern "C" void kernel_launch(void* const* d_in, const int* in_sizes, int n_in,
                              void* d_out, int out_size, void* d_ws, size_t ws_size,
                              hipStream_t stream) {
    const float* inp = (const float*)d_in[0];
    const float* F   = (const float*)d_in[1];
    const float* H   = (const float*)d_in[2];
    const float* Q   = (const float*)d_in[3];
    const float* R   = (const float*)d_in[4];
    const float* m0  = (const float*)d_in[5];
    const float* P0  = (const float*)d_in[6];
    float* out = (float*)d_out;

    dim3 grid((BN * MM) / BLOCK), block(BLOCK);
    hipLaunchKernelGGL(kf_kernel, grid, block, 0, stream,
                       inp, F, H, Q, R, m0, P0, out);
}

// Round 4
// 912.379 us; speedup vs baseline: 1.5554x; 1.5554x over previous
//
#include <hip/hip_runtime.h>

#define BN 16384
#define TT 128
#define MM 4
#define SS 12
#define BLOCK 64
#define NSER (BLOCK / 4)    // 16 series per block (one wave)
#define TSTRIDE 145         // doubles per series region: 290 dwords % 32 = 2 -> perfect bank-pair spread

__global__ __launch_bounds__(BLOCK, 1) void kf_kernel(
    const float* __restrict__ inp,   // [B][T][M]
    const float* __restrict__ Fm,    // [S][S]
    const float* __restrict__ Hm,    // [M][S]
    const float* __restrict__ Qm,    // [S][S]
    const float* __restrict__ Rm,    // [M][M]
    const float* __restrict__ m0p,   // [B][S]
    const float* __restrict__ P0p,   // [B][S][S]
    float* __restrict__ outp)        // [T][B][M]
{
    __shared__ double Fd[SS * SS];
    __shared__ double Hd[MM * SS];
    __shared__ double Qd[SS * SS];
    __shared__ double Rd[MM * MM];
    __shared__ double tb[NSER * TSTRIDE];

    const int tid  = threadIdx.x;
    const int gid  = blockIdx.x * BLOCK + tid;
    const int b    = gid >> 2;        // series
    const int c    = gid & 3;         // quad sub-lane: owns P columns {3c,3c+1,3c+2}
    const int sb   = tid >> 2;        // series-in-block
    const int col0 = 3 * c;

    for (int i = tid; i < SS * SS; i += BLOCK) {
        Fd[i] = (double)Fm[i];
        Qd[i] = (double)Qm[i];
    }
    if (tid < MM * SS) Hd[tid] = (double)Hm[tid];
    if (tid < MM * MM) Rd[tid] = (double)Rm[tid];

    // persistent per-lane state: mean (full) + own 3 columns of symmetric P
    double m[SS];
#pragma unroll
    for (int s = 0; s < SS; ++s) m[s] = (double)m0p[b * SS + s];

    double P[SS][3];
#pragma unroll
    for (int s = 0; s < SS; ++s)
#pragma unroll
        for (int jj = 0; jj < 3; ++jj)
            P[s][jj] = (double)P0p[b * SS * SS + s * SS + col0 + jj];

    const float* op = inp + b * (TT * MM) + c;  // own measurement stream
    float obn = op[0];
    double* tser = &tb[sb * TSTRIDE];

    __syncthreads();  // constants ready (single-wave WG: cheap)

#pragma unroll 1
    for (int t = 0; t < TT; ++t) {
        // ---------- GEMM1: mv = F m ; U-row i = F[i,:]*P(local cols) -> LDS ----------
        double mv[SS];
        __syncthreads();  // prev iteration's tser reads complete
#pragma unroll
        for (int i = 0; i < SS; ++i) {
            double fr[SS];
#pragma unroll
            for (int s = 0; s < SS; ++s) fr[s] = Fd[i * SS + s];
            double a = 0.0, u0 = 0.0, u1 = 0.0, u2 = 0.0;
#pragma unroll
            for (int s = 0; s < SS; ++s) {
                a  += fr[s] * m[s];
                u0 += fr[s] * P[s][0];
                u1 += fr[s] * P[s][1];
                u2 += fr[s] * P[s][2];
            }
            mv[i] = a;
            tser[i * SS + col0 + 0] = u0;
            tser[i * SS + col0 + 1] = u1;
            tser[i * SS + col0 + 2] = u2;
        }
        __syncthreads();

        // ---------- GEMM2 (split-K): P <- Q + U * F^T  (prior cov, in place) -------
#pragma unroll
        for (int h = 0; h < 2; ++h) {
            double Ur[3][6];
#pragma unroll
            for (int jj = 0; jj < 3; ++jj)
#pragma unroll
                for (int kk = 0; kk < 6; ++kk)
                    Ur[jj][kk] = tser[(col0 + jj) * SS + h * 6 + kk];
#pragma unroll
            for (int s = 0; s < SS; ++s) {
                double fr6[6];
#pragma unroll
                for (int kk = 0; kk < 6; ++kk) fr6[kk] = Fd[s * SS + h * 6 + kk];
                double p0 = (h == 0) ? Qd[s * SS + col0 + 0] : P[s][0];
                double p1 = (h == 0) ? Qd[s * SS + col0 + 1] : P[s][1];
                double p2 = (h == 0) ? Qd[s * SS + col0 + 2] : P[s][2];
#pragma unroll
                for (int kk = 0; kk < 6; ++kk) {
                    p0 += Ur[0][kk] * fr6[kk];
                    p1 += Ur[1][kk] * fr6[kk];
                    p2 += Ur[2][kk] * fr6[kk];
                }
                P[s][0] = p0; P[s][1] = p1; P[s][2] = p2;
            }
        }

        // ---------- y (own row only) + store + residual broadcast ----------
        double y = 0.0;
#pragma unroll
        for (int s = 0; s < SS; ++s) y += Hd[c * SS + s] * mv[s];
        outp[t * (BN * MM) + b * MM + c] = (float)y;

        float obc = obn;
        if (t + 1 < TT) obn = op[(t + 1) * MM];  // prefetch next obs

        double rc = (double)obc - y;
        double r0 = __shfl(rc, 0, 4), r1 = __shfl(rc, 1, 4);
        double r2 = __shfl(rc, 2, 4), r3 = __shfl(rc, 3, 4);

        // ---------- HP = H * P_prior (local cols) ----------
        double HPl[MM][3];
#pragma unroll
        for (int n = 0; n < MM; ++n) {
            double h0 = 0.0, h1 = 0.0, h2 = 0.0;
#pragma unroll
            for (int s = 0; s < SS; ++s) {
                double hv = Hd[n * SS + s];
                h0 += hv * P[s][0]; h1 += hv * P[s][1]; h2 += hv * P[s][2];
            }
            HPl[n][0] = h0; HPl[n][1] = h1; HPl[n][2] = h2;
        }

        // ---------- innovation cov: local partial + quad butterfly ----------
        double Su[10];
        {
            int u = 0;
#pragma unroll
            for (int n = 0; n < MM; ++n)
#pragma unroll
                for (int t2 = n; t2 < MM; ++t2) {
                    double acc = HPl[n][0] * Hd[t2 * SS + col0 + 0]
                               + HPl[n][1] * Hd[t2 * SS + col0 + 1]
                               + HPl[n][2] * Hd[t2 * SS + col0 + 2];
                    acc += __shfl_xor(acc, 1, 4);
                    acc += __shfl_xor(acc, 2, 4);
                    Su[u++] = acc + Rd[n * MM + t2];
                }
        }
        double s00 = Su[0], s01 = Su[1], s02 = Su[2], s03 = Su[3];
        double s11 = Su[4], s12 = Su[5], s13 = Su[6];
        double s22 = Su[7], s23 = Su[8], s33 = Su[9];

        // ---------- symmetric 4x4 inverse via 2x2 Schur (fp64) ----------
        double ra   = 1.0 / (s00 * s11 - s01 * s01);
        double ai00 = s11 * ra, ai01 = -s01 * ra, ai11 = s00 * ra;
        double w00 = ai00 * s02 + ai01 * s12;
        double w01 = ai00 * s03 + ai01 * s13;
        double w10 = ai01 * s02 + ai11 * s12;
        double w11 = ai01 * s03 + ai11 * s13;
        double e00 = s22 - (s02 * w00 + s12 * w10);
        double e01 = s23 - (s02 * w01 + s12 * w11);
        double e11 = s33 - (s03 * w01 + s13 * w11);
        double rmm = 1.0 / (e00 * e11 - e01 * e01);
        double q22 = e11 * rmm, q23 = -e01 * rmm, q33 = e00 * rmm;
        double x00 = w00 * q22 + w01 * q23;
        double x01 = w00 * q23 + w01 * q33;
        double x10 = w10 * q22 + w11 * q23;
        double x11 = w10 * q23 + w11 * q33;
        double q00 = ai00 + x00 * w00 + x01 * w01;
        double q01 = ai01 + x00 * w10 + x01 * w11;
        double q11 = ai11 + x10 * w10 + x11 * w11;
        double Qi[MM][MM] = {
            { q00,  q01,  -x00, -x01 },
            { q01,  q11,  -x10, -x11 },
            { -x00, -x10,  q22,  q23 },
            { -x01, -x11,  q23,  q33 }
        };

        // ---------- z = Sinv r ; mean update (no K materialized) ----------
        double z0 = Qi[0][0] * r0 + Qi[0][1] * r1 + Qi[0][2] * r2 + Qi[0][3] * r3;
        double z1 = Qi[1][0] * r0 + Qi[1][1] * r1 + Qi[1][2] * r2 + Qi[1][3] * r3;
        double z2 = Qi[2][0] * r0 + Qi[2][1] * r1 + Qi[2][2] * r2 + Qi[2][3] * r3;
        double z3 = Qi[3][0] * r0 + Qi[3][1] * r1 + Qi[3][2] * r2 + Qi[3][3] * r3;

        double upd[3];
#pragma unroll
        for (int jj = 0; jj < 3; ++jj)
            upd[jj] = HPl[0][jj] * z0 + HPl[1][jj] * z1
                    + HPl[2][jj] * z2 + HPl[3][jj] * z3;

        // all-gather updated mean: source lane k/3 supplies mv[k]+upd[k%3]
#pragma unroll
        for (int k = 0; k < SS; ++k)
            m[k] = __shfl(mv[k] + upd[k % 3], k / 3, 4);

        // ---------- covariance update: P -= (HP)^T Sinv (HP) ----------
        double G[MM][3];  // G = Sinv * HP (local cols)
#pragma unroll
        for (int n = 0; n < MM; ++n)
#pragma unroll
            for (int jj = 0; jj < 3; ++jj)
                G[n][jj] = Qi[n][0] * HPl[0][jj] + Qi[n][1] * HPl[1][jj]
                         + Qi[n][2] * HPl[2][jj] + Qi[n][3] * HPl[3][jj];

#pragma unroll
        for (int s = 0; s < SS; ++s) {
            double h0 = __shfl(HPl[0][s % 3], s / 3, 4);
            double h1 = __shfl(HPl[1][s % 3], s / 3, 4);
            double h2 = __shfl(HPl[2][s % 3], s / 3, 4);
            double h3 = __shfl(HPl[3][s % 3], s / 3, 4);
#pragma unroll
            for (int jj = 0; jj < 3; ++jj)
                P[s][jj] -= h0 * G[0][jj] + h1 * G[1][jj]
                          + h2 * G[2][jj] + h3 * G[3][jj];
        }
    }
}

extern "C" void kernel_launch(void* const* d_in, const int* in_sizes, int n_in,
                              void* d_out, int out_size, void* d_ws, size_t ws_size,
                              hipStream_t stream) {
    const float* inp = (const float*)d_in[0];
    const float* F   = (const float*)d_in[1];
    const float* H   = (const float*)d_in[2];
    const float* Q   = (const float*)d_in[3];
    const float* R   = (const float*)d_in[4];
    const float* m0  = (const float*)d_in[5];
    const float* P0  = (const float*)d_in[6];
    float* out = (float*)d_out;

    dim3 grid((BN * MM) / BLOCK), block(BLOCK);
    hipLaunchKernelGGL(kf_kernel, grid, block, 0, stream,
                       inp, F, H, Q, R, m0, P0, out);
}